// Round 7
// baseline (1103.759 us; speedup 1.0000x reference)
//
#include <hip/hip_runtime.h>
#include <math.h>

#define BS_TOT 32768
#define NN 30
#define HHD 8
#define GHH 16
#define LHH 64
#define SSS 512
#define BBB 64
#define RECON_SIZE (BBB*SSS*NN)   // 983040

__device__ __forceinline__ float fsigmoid(float x) {
    return 1.f / (1.f + __expf(-x));
}
__device__ __forceinline__ float ftanh(float x) {
    float ax = fabsf(x);
    float e = __expf(-2.f * ax);
    float r = (1.f - e) / (1.f + e);
    return copysignf(r, x);
}
__device__ __forceinline__ float rdlane(float v, int l) {
    return __int_as_float(__builtin_amdgcn_readlane(__float_as_int(v), l));
}

// ---------------- K1: GAT + projection (fused) ----------------
#define NB 16
__global__ __launch_bounds__(256) void gat_proj_kernel(
    const float* __restrict__ x, const float* __restrict__ adj,
    const float* __restrict__ W_gat, const float* __restrict__ a_src,
    const float* __restrict__ a_dst, const float* __restrict__ W_proj,
    const float* __restrict__ b_proj, float* __restrict__ gat_seq,
    float* __restrict__ attn_out)
{
    __shared__ __align__(16) float gat[NB][480];
    __shared__ __align__(16) float wchunk[96*64];
    __shared__ float x_s[NB][32];
    __shared__ unsigned adjbits[32];

    const int t = threadIdx.x;
    const int bs_base = blockIdx.x * NB;

    for (int rep = 0; rep < 2; ++rep) {
        int idx = rep*256 + t;
        int bl = idx >> 5, j = idx & 31;
        if (j < NN) x_s[bl][j] = x[(bs_base + bl)*NN + j];
    }
    if (t < NN) {
        unsigned bits = 0;
        for (int j = 0; j < NN; ++j)
            if (adj[t*NN + j] != 0.0f) bits |= (1u << j);
        adjbits[t] = bits;
    }
    __syncthreads();

    const int wave = t >> 6, lane = t & 63;
    const int h = lane >> 5, i = lane & 31;
    const bool act = (i < NN);

    float wg[HHD];
    float s_h = 0.f, t_h = 0.f;
    #pragma unroll
    for (int d = 0; d < HHD; ++d) {
        float w = W_gat[h*HHD + d];
        wg[d] = w;
        s_h += w * a_src[h*HHD + d];
        t_h += w * a_dst[h*HHD + d];
    }

    for (int r = 0; r < 4; ++r) {
        const int bl = wave*4 + r;
        const int bs = bs_base + bl;
        const unsigned bits = act ? adjbits[i & 31] : 0u;
        const float xi = act ? x_s[bl][i] : 0.f;
        const float esrc = xi * s_h;

        float m = -1e30f;
        for (int j = 0; j < NN; ++j) {
            if (bits & (1u << j)) {
                float e = esrc + x_s[bl][j] * t_h;
                e = (e >= 0.f) ? e : 0.2f * e;
                m = fmaxf(m, e);
            }
        }
        float Z = 0.f, Sx = 0.f;
        for (int j = 0; j < NN; ++j) {
            if (bits & (1u << j)) {
                float e = esrc + x_s[bl][j] * t_h;
                e = (e >= 0.f) ? e : 0.2f * e;
                float p = expf(e - m);
                Z += p;
                Sx += p * x_s[bl][j];
            }
        }
        const float wsum = Sx / Z;

        if (act) {
            float tmp[8];
            #pragma unroll
            for (int d = 0; d < 8; ++d) {
                float v = wsum * wg[d];
                tmp[d] = (v > 0.f) ? v : expm1f(v);
            }
            float4 v0 = make_float4(tmp[0], tmp[1], tmp[2], tmp[3]);
            float4 v1 = make_float4(tmp[4], tmp[5], tmp[6], tmp[7]);
            *(float4*)&gat[bl][i*GHH + h*HHD]     = v0;
            *(float4*)&gat[bl][i*GHH + h*HHD + 4] = v1;
        }

        if ((bs & (SSS-1)) == (SSS-1)) {
            const int b = bs >> 9;
            for (int j = 0; j < NN; ++j) {
                float a = 0.f;
                if (bits & (1u << j)) {
                    float e = esrc + x_s[bl][j] * t_h;
                    e = (e >= 0.f) ? e : 0.2f * e;
                    a = expf(e - m) / Z;
                }
                float ao = __shfl_xor(a, 32, 64);
                if (act && h == 0)
                    attn_out[b*(NN*NN) + i*NN + j] = 0.5f * (a + ao);
            }
        }
    }
    __syncthreads();

    const int p = t & 63, grp = t >> 6;
    float acc0 = 0.f, acc1 = 0.f, acc2 = 0.f, acc3 = 0.f;
    for (int c = 0; c < 5; ++c) {
        #pragma unroll
        for (int rep = 0; rep < 24; ++rep)
            wchunk[rep*256 + t] = W_proj[c*6144 + rep*256 + t];
        __syncthreads();
        for (int kk = 0; kk < 96; kk += 4) {
            float4 g0 = *(const float4*)&gat[grp*4 + 0][c*96 + kk];
            float4 g1 = *(const float4*)&gat[grp*4 + 1][c*96 + kk];
            float4 g2 = *(const float4*)&gat[grp*4 + 2][c*96 + kk];
            float4 g3 = *(const float4*)&gat[grp*4 + 3][c*96 + kk];
            float w0 = wchunk[(kk+0)*64 + p];
            float w1 = wchunk[(kk+1)*64 + p];
            float w2 = wchunk[(kk+2)*64 + p];
            float w3 = wchunk[(kk+3)*64 + p];
            acc0 += g0.x*w0 + g0.y*w1 + g0.z*w2 + g0.w*w3;
            acc1 += g1.x*w0 + g1.y*w1 + g1.z*w2 + g1.w*w3;
            acc2 += g2.x*w0 + g2.y*w1 + g2.z*w2 + g2.w*w3;
            acc3 += g3.x*w0 + g3.y*w1 + g3.z*w2 + g3.w*w3;
        }
        __syncthreads();
    }
    const float bp = b_proj[p];
    gat_seq[(bs_base + grp*4 + 0)*64 + p] = fmaxf(acc0 + bp, 0.f);
    gat_seq[(bs_base + grp*4 + 1)*64 + p] = fmaxf(acc1 + bp, 0.f);
    gat_seq[(bs_base + grp*4 + 2)*64 + p] = fmaxf(acc2 + bp, 0.f);
    gat_seq[(bs_base + grp*4 + 3)*64 + p] = fmaxf(acc3 + bp, 0.f);
}

// ------- K2: one LSTM layer; 256 threads = 256 gate rows; readlane bcast ----
// R4 evidence: 256-thread + __launch_bounds__(256,1) is the ONE regime where
// the allocator grants a large VGPR allocation (220). Per-thread demand here
// is 128 weight floats + ~30 overhead -> fits without spill.
// Input broadcast: 2x ds_read_b32 per wave loads [x_t; h] into lanes, then
// 128 v_readlane -> SGPR, consumed by v_fmac v,s,v (1 SGPR operand is legal).
// This removes the 256 wave-level ds_read_b128/step (~2500 cyc, the real
// bottleneck of R2-R6) from the LDS pipe entirely.
__global__ __launch_bounds__(256, 1) void lstm_layer_reg_kernel(
    const float* __restrict__ xin, const float* __restrict__ W_ih,
    const float* __restrict__ W_hh, const float* __restrict__ b_ih,
    const float* __restrict__ b_hh, float* __restrict__ h_out)
{
    __shared__ float xh[128];      // [0:64]=x_t, [64:128]=h_{t-1}
    __shared__ float gates[256];

    const int t = threadIdx.x;
    const int b = blockIdx.x;
    const int lane = t & 63;

    const float* wip = W_ih + t*64;
    const float* whp = W_hh + t*64;

#define LOADW(i) \
    float4 wi##i = *(const float4*)(wip + 4*(i)); \
    float4 wh##i = *(const float4*)(whp + 4*(i));
    LOADW(0)  LOADW(1)  LOADW(2)  LOADW(3)
    LOADW(4)  LOADW(5)  LOADW(6)  LOADW(7)
    LOADW(8)  LOADW(9)  LOADW(10) LOADW(11)
    LOADW(12) LOADW(13) LOADW(14) LOADW(15)
#undef LOADW

#define PIN(i) asm volatile("" \
    : "+v"(wi##i.x), "+v"(wi##i.y), "+v"(wi##i.z), "+v"(wi##i.w), \
      "+v"(wh##i.x), "+v"(wh##i.y), "+v"(wh##i.z), "+v"(wh##i.w));
    PIN(0)  PIN(1)  PIN(2)  PIN(3)  PIN(4)  PIN(5)  PIN(6)  PIN(7)
    PIN(8)  PIN(9)  PIN(10) PIN(11) PIN(12) PIN(13) PIN(14) PIN(15)
#undef PIN

    const float bsum = b_ih[t] + b_hh[t];

    if (t >= 64 && t < 128) xh[t] = 0.f;   // zero h state
    const float* __restrict__ xrow = xin + (size_t)b * SSS * 64;
    float* __restrict__ hrow = h_out + (size_t)b * SSS * 64;

    float c = 0.f;
    float xreg = (t < 64) ? xrow[t] : 0.f;
    const int sect = t >> 6;

    for (int tt = 0; tt < SSS; ++tt) {
        if (t < 64) xh[t] = xreg;
        __syncthreads();
        if (t < 64 && tt + 1 < SSS) xreg = xrow[(tt+1)*64 + t];

        // per-wave: pull the 128-vector into lanes (2 conflict-free b32 reads)
        float vx0 = xh[lane];
        float vx1 = xh[64 + lane];

        float a0 = 0.f, a1 = 0.f, a2 = 0.f, a3 = 0.f;
#define RLX(i) { \
        float s0 = rdlane(vx0, 4*(i)+0); float s1 = rdlane(vx0, 4*(i)+1); \
        float s2 = rdlane(vx0, 4*(i)+2); float s3 = rdlane(vx0, 4*(i)+3); \
        a0 = fmaf(s0, wi##i.x, a0); a1 = fmaf(s1, wi##i.y, a1); \
        a2 = fmaf(s2, wi##i.z, a2); a3 = fmaf(s3, wi##i.w, a3); }
#define RLH(i) { \
        float s0 = rdlane(vx1, 4*(i)+0); float s1 = rdlane(vx1, 4*(i)+1); \
        float s2 = rdlane(vx1, 4*(i)+2); float s3 = rdlane(vx1, 4*(i)+3); \
        a0 = fmaf(s0, wh##i.x, a0); a1 = fmaf(s1, wh##i.y, a1); \
        a2 = fmaf(s2, wh##i.z, a2); a3 = fmaf(s3, wh##i.w, a3); }
        RLX(0)  RLX(1)  RLX(2)  RLX(3)  RLX(4)  RLX(5)  RLX(6)  RLX(7)
        RLX(8)  RLX(9)  RLX(10) RLX(11) RLX(12) RLX(13) RLX(14) RLX(15)
        RLH(0)  RLH(1)  RLH(2)  RLH(3)  RLH(4)  RLH(5)  RLH(6)  RLH(7)
        RLH(8)  RLH(9)  RLH(10) RLH(11) RLH(12) RLH(13) RLH(14) RLH(15)
#undef RLX
#undef RLH
        const float acc = bsum + ((a0 + a1) + (a2 + a3));
        float a = (sect == 2) ? ftanh(acc) : fsigmoid(acc);
        gates[t] = a;
        __syncthreads();

        if (t < 64) {
            float ig = gates[t], fg = gates[64+t], gg = gates[128+t], og = gates[192+t];
            c = fg*c + ig*gg;
            float hv = og * ftanh(c);
            xh[64 + t] = hv;
            hrow[(size_t)tt*64 + t] = hv;
        }
    }
}

// ---------------- K3: recon = h2 @ W_out + b_out ----------------
__global__ __launch_bounds__(256) void recon_kernel(
    const float* __restrict__ h2, const float* __restrict__ W_out,
    const float* __restrict__ b_out, float* __restrict__ out)
{
    __shared__ __align__(16) float hl[8*64];
    const int t = threadIdx.x;
    const int bs_base = blockIdx.x * 8;

    hl[t]       = h2[(size_t)bs_base*64 + t];
    hl[256 + t] = h2[(size_t)bs_base*64 + 256 + t];
    __syncthreads();

    if (t < 240) {
        const int bl = t / 30;
        const int n  = t - bl*30;
        float acc = b_out[n];
        #pragma unroll
        for (int k = 0; k < 64; ++k)
            acc += hl[bl*64 + k] * W_out[k*NN + n];
        out[(size_t)(bs_base + bl)*NN + n] = acc;
    }
}

extern "C" void kernel_launch(void* const* d_in, const int* in_sizes, int n_in,
                              void* d_out, int out_size, void* d_ws, size_t ws_size,
                              hipStream_t stream)
{
    const float* x      = (const float*)d_in[0];
    const float* adj    = (const float*)d_in[1];
    const float* W_gat  = (const float*)d_in[2];
    const float* a_src  = (const float*)d_in[3];
    const float* a_dst  = (const float*)d_in[4];
    const float* W_proj = (const float*)d_in[5];
    const float* b_proj = (const float*)d_in[6];
    const float* W_ih0  = (const float*)d_in[7];
    const float* W_hh0  = (const float*)d_in[8];
    const float* b_ih0  = (const float*)d_in[9];
    const float* b_hh0  = (const float*)d_in[10];
    const float* W_ih1  = (const float*)d_in[11];
    const float* W_hh1  = (const float*)d_in[12];
    const float* b_ih1  = (const float*)d_in[13];
    const float* b_hh1  = (const float*)d_in[14];
    const float* W_out  = (const float*)d_in[15];
    const float* b_out  = (const float*)d_in[16];

    float* out = (float*)d_out;
    float* gat_seq = (float*)d_ws;                 //  8.4 MB
    float* h1 = gat_seq + (size_t)BS_TOT*64;       //  8.4 MB
    float* h2 = h1 + (size_t)BS_TOT*64;            //  8.4 MB

    hipLaunchKernelGGL(gat_proj_kernel, dim3(BS_TOT/NB), dim3(256), 0, stream,
                       x, adj, W_gat, a_src, a_dst, W_proj, b_proj,
                       gat_seq, out + RECON_SIZE);
    hipLaunchKernelGGL(lstm_layer_reg_kernel, dim3(BBB), dim3(256), 0, stream,
                       gat_seq, W_ih0, W_hh0, b_ih0, b_hh0, h1);
    hipLaunchKernelGGL(lstm_layer_reg_kernel, dim3(BBB), dim3(256), 0, stream,
                       h1, W_ih1, W_hh1, b_ih1, b_hh1, h2);
    hipLaunchKernelGGL(recon_kernel, dim3(BS_TOT/8), dim3(256), 0, stream,
                       h2, W_out, b_out, out);
}

// Round 8
// 909.636 us; speedup vs baseline: 1.2134x; 1.2134x over previous
//
#include <hip/hip_runtime.h>
#include <math.h>

#define BS_TOT 32768
#define NN 30
#define HHD 8
#define GHH 16
#define LHH 64
#define SSS 512
#define BBB 64
#define RECON_SIZE (BBB*SSS*NN)   // 983040

__device__ __forceinline__ float fsigmoid(float x) {
    return 1.f / (1.f + __expf(-x));
}
__device__ __forceinline__ float ftanh(float x) {
    float ax = fabsf(x);
    float e = __expf(-2.f * ax);
    float r = (1.f - e) / (1.f + e);
    return copysignf(r, x);
}

// ---------------- K1: GAT + projection (fused) ----------------
#define NB 16
__global__ __launch_bounds__(256) void gat_proj_kernel(
    const float* __restrict__ x, const float* __restrict__ adj,
    const float* __restrict__ W_gat, const float* __restrict__ a_src,
    const float* __restrict__ a_dst, const float* __restrict__ W_proj,
    const float* __restrict__ b_proj, float* __restrict__ gat_seq,
    float* __restrict__ attn_out)
{
    __shared__ __align__(16) float gat[NB][480];
    __shared__ __align__(16) float wchunk[96*64];
    __shared__ float x_s[NB][32];
    __shared__ unsigned adjbits[32];

    const int t = threadIdx.x;
    const int bs_base = blockIdx.x * NB;

    for (int rep = 0; rep < 2; ++rep) {
        int idx = rep*256 + t;
        int bl = idx >> 5, j = idx & 31;
        if (j < NN) x_s[bl][j] = x[(bs_base + bl)*NN + j];
    }
    if (t < NN) {
        unsigned bits = 0;
        for (int j = 0; j < NN; ++j)
            if (adj[t*NN + j] != 0.0f) bits |= (1u << j);
        adjbits[t] = bits;
    }
    __syncthreads();

    const int wave = t >> 6, lane = t & 63;
    const int h = lane >> 5, i = lane & 31;
    const bool act = (i < NN);

    float wg[HHD];
    float s_h = 0.f, t_h = 0.f;
    #pragma unroll
    for (int d = 0; d < HHD; ++d) {
        float w = W_gat[h*HHD + d];
        wg[d] = w;
        s_h += w * a_src[h*HHD + d];
        t_h += w * a_dst[h*HHD + d];
    }

    for (int r = 0; r < 4; ++r) {
        const int bl = wave*4 + r;
        const int bs = bs_base + bl;
        const unsigned bits = act ? adjbits[i & 31] : 0u;
        const float xi = act ? x_s[bl][i] : 0.f;
        const float esrc = xi * s_h;

        float m = -1e30f;
        for (int j = 0; j < NN; ++j) {
            if (bits & (1u << j)) {
                float e = esrc + x_s[bl][j] * t_h;
                e = (e >= 0.f) ? e : 0.2f * e;
                m = fmaxf(m, e);
            }
        }
        float Z = 0.f, Sx = 0.f;
        for (int j = 0; j < NN; ++j) {
            if (bits & (1u << j)) {
                float e = esrc + x_s[bl][j] * t_h;
                e = (e >= 0.f) ? e : 0.2f * e;
                float p = expf(e - m);
                Z += p;
                Sx += p * x_s[bl][j];
            }
        }
        const float wsum = Sx / Z;

        if (act) {
            float tmp[8];
            #pragma unroll
            for (int d = 0; d < 8; ++d) {
                float v = wsum * wg[d];
                tmp[d] = (v > 0.f) ? v : expm1f(v);
            }
            float4 v0 = make_float4(tmp[0], tmp[1], tmp[2], tmp[3]);
            float4 v1 = make_float4(tmp[4], tmp[5], tmp[6], tmp[7]);
            *(float4*)&gat[bl][i*GHH + h*HHD]     = v0;
            *(float4*)&gat[bl][i*GHH + h*HHD + 4] = v1;
        }

        if ((bs & (SSS-1)) == (SSS-1)) {
            const int b = bs >> 9;
            for (int j = 0; j < NN; ++j) {
                float a = 0.f;
                if (bits & (1u << j)) {
                    float e = esrc + x_s[bl][j] * t_h;
                    e = (e >= 0.f) ? e : 0.2f * e;
                    a = expf(e - m) / Z;
                }
                float ao = __shfl_xor(a, 32, 64);
                if (act && h == 0)
                    attn_out[b*(NN*NN) + i*NN + j] = 0.5f * (a + ao);
            }
        }
    }
    __syncthreads();

    const int p = t & 63, grp = t >> 6;
    float acc0 = 0.f, acc1 = 0.f, acc2 = 0.f, acc3 = 0.f;
    for (int c = 0; c < 5; ++c) {
        #pragma unroll
        for (int rep = 0; rep < 24; ++rep)
            wchunk[rep*256 + t] = W_proj[c*6144 + rep*256 + t];
        __syncthreads();
        for (int kk = 0; kk < 96; kk += 4) {
            float4 g0 = *(const float4*)&gat[grp*4 + 0][c*96 + kk];
            float4 g1 = *(const float4*)&gat[grp*4 + 1][c*96 + kk];
            float4 g2 = *(const float4*)&gat[grp*4 + 2][c*96 + kk];
            float4 g3 = *(const float4*)&gat[grp*4 + 3][c*96 + kk];
            float w0 = wchunk[(kk+0)*64 + p];
            float w1 = wchunk[(kk+1)*64 + p];
            float w2 = wchunk[(kk+2)*64 + p];
            float w3 = wchunk[(kk+3)*64 + p];
            acc0 += g0.x*w0 + g0.y*w1 + g0.z*w2 + g0.w*w3;
            acc1 += g1.x*w0 + g1.y*w1 + g1.z*w2 + g1.w*w3;
            acc2 += g2.x*w0 + g2.y*w1 + g2.z*w2 + g2.w*w3;
            acc3 += g3.x*w0 + g3.y*w1 + g3.z*w2 + g3.w*w3;
        }
        __syncthreads();
    }
    const float bp = b_proj[p];
    gat_seq[(bs_base + grp*4 + 0)*64 + p] = fmaxf(acc0 + bp, 0.f);
    gat_seq[(bs_base + grp*4 + 1)*64 + p] = fmaxf(acc1 + bp, 0.f);
    gat_seq[(bs_base + grp*4 + 2)*64 + p] = fmaxf(acc2 + bp, 0.f);
    gat_seq[(bs_base + grp*4 + 3)*64 + p] = fmaxf(acc3 + bp, 0.f);
}

// ------- K2a: input projection (no recurrence -> fully parallel GEMM) -------
// gx[bs][g] = b_ih[g] + b_hh[g] + sum_k xin[bs][k] * W[g][k]
// One WG per 64 rows; x tile staged in LDS (broadcast reads), W row in regs.
__global__ __launch_bounds__(256) void xproj_kernel(
    const float* __restrict__ xin,   // (BS, 64)
    const float* __restrict__ W,     // (256, 64) row-major
    const float* __restrict__ b_ih, const float* __restrict__ b_hh,
    float* __restrict__ gx)          // (BS, 256)
{
    __shared__ __align__(16) float xt[64][64];   // 16 KB
    const int t = threadIdx.x;
    const int r0 = blockIdx.x * 64;

    for (int i = t; i < 64*16; i += 256) {       // float4 units
        int r = i >> 4, c4 = (i & 15) << 2;
        *(float4*)&xt[r][c4] = *(const float4*)&xin[(size_t)(r0 + r)*64 + c4];
    }
    float4 w[16];
    #pragma unroll
    for (int i = 0; i < 16; ++i) w[i] = *(const float4*)&W[t*64 + 4*i];
    const float bias = b_ih[t] + b_hh[t];
    __syncthreads();

    for (int r = 0; r < 64; ++r) {
        float a0 = 0.f, a1 = 0.f, a2 = 0.f, a3 = 0.f;
        #pragma unroll
        for (int i = 0; i < 16; ++i) {
            float4 v = *(const float4*)&xt[r][4*i];   // wave-uniform -> broadcast
            a0 = fmaf(v.x, w[i].x, a0); a1 = fmaf(v.y, w[i].y, a1);
            a2 = fmaf(v.z, w[i].z, a2); a3 = fmaf(v.w, w[i].w, a3);
        }
        gx[(size_t)(r0 + r)*256 + t] = bias + ((a0 + a1) + (a2 + a3));
    }
}

// ------- K2b: LSTM recurrence, W_hh resident in LDS (cannot be spilled) -----
// One WG (256 thr) per batch element; thread t = gate row t. Per step:
// 16 ds_read_b128 of the thread's W_hh row (64 KB/WG/step, LDS-BW floor) +
// 16 broadcast b128 of h + 64 FMA. gx (precomputed x-part incl. biases)
// streams from global with a one-step register prefetch.
__global__ __launch_bounds__(256) void lstm_rec_kernel(
    const float* __restrict__ gx,    // (B, S, 256)
    const float* __restrict__ W_hh,  // (256, 64)
    float* __restrict__ h_out)       // (B, S, 64)
{
    __shared__ __align__(16) float whh[256][68];  // pad 64->68: bank spread, 16B-aligned rows
    __shared__ float h_s[64];
    __shared__ float gates[256];

    const int t = threadIdx.x;
    const int b = blockIdx.x;

    for (int i = t; i < 256*16; i += 256) {       // float4 units
        int r = i >> 4, c4 = (i & 15) << 2;
        *(float4*)&whh[r][c4] = *(const float4*)&W_hh[r*64 + c4];
    }
    if (t < 64) h_s[t] = 0.f;
    __syncthreads();

    const float* __restrict__ gxb = gx + (size_t)b * SSS * 256;
    float* __restrict__ hrow = h_out + (size_t)b * SSS * 64;

    float c = 0.f;
    float gx_cur = gxb[t];
    const int sect = t >> 6;     // 0:i 1:f 2:g 3:o

    for (int tt = 0; tt < SSS; ++tt) {
        float gx_next = (tt + 1 < SSS) ? gxb[(size_t)(tt+1)*256 + t] : 0.f;

        float a0 = 0.f, a1 = 0.f, a2 = 0.f, a3 = 0.f;
        #pragma unroll
        for (int i = 0; i < 16; ++i) {
            float4 h4 = *(const float4*)&h_s[4*i];     // broadcast (uniform addr)
            float4 w4 = *(const float4*)&whh[t][4*i];  // per-thread row
            a0 = fmaf(h4.x, w4.x, a0); a1 = fmaf(h4.y, w4.y, a1);
            a2 = fmaf(h4.z, w4.z, a2); a3 = fmaf(h4.w, w4.w, a3);
        }
        const float acc = gx_cur + ((a0 + a1) + (a2 + a3));
        const float a = (sect == 2) ? ftanh(acc) : fsigmoid(acc);
        gates[t] = a;
        __syncthreads();

        if (t < 64) {
            float ig = gates[t], fg = gates[64+t], gg = gates[128+t], og = gates[192+t];
            c = fg*c + ig*gg;
            float hv = og * ftanh(c);
            h_s[t] = hv;
            hrow[(size_t)tt*64 + t] = hv;
        }
        gx_cur = gx_next;
        __syncthreads();
    }
}

// ---------------- K3: recon = h2 @ W_out + b_out ----------------
__global__ __launch_bounds__(256) void recon_kernel(
    const float* __restrict__ h2, const float* __restrict__ W_out,
    const float* __restrict__ b_out, float* __restrict__ out)
{
    __shared__ __align__(16) float hl[8*64];
    const int t = threadIdx.x;
    const int bs_base = blockIdx.x * 8;

    hl[t]       = h2[(size_t)bs_base*64 + t];
    hl[256 + t] = h2[(size_t)bs_base*64 + 256 + t];
    __syncthreads();

    if (t < 240) {
        const int bl = t / 30;
        const int n  = t - bl*30;
        float acc = b_out[n];
        #pragma unroll
        for (int k = 0; k < 64; ++k)
            acc += hl[bl*64 + k] * W_out[k*NN + n];
        out[(size_t)(bs_base + bl)*NN + n] = acc;
    }
}

extern "C" void kernel_launch(void* const* d_in, const int* in_sizes, int n_in,
                              void* d_out, int out_size, void* d_ws, size_t ws_size,
                              hipStream_t stream)
{
    const float* x      = (const float*)d_in[0];
    const float* adj    = (const float*)d_in[1];
    const float* W_gat  = (const float*)d_in[2];
    const float* a_src  = (const float*)d_in[3];
    const float* a_dst  = (const float*)d_in[4];
    const float* W_proj = (const float*)d_in[5];
    const float* b_proj = (const float*)d_in[6];
    const float* W_ih0  = (const float*)d_in[7];
    const float* W_hh0  = (const float*)d_in[8];
    const float* b_ih0  = (const float*)d_in[9];
    const float* b_hh0  = (const float*)d_in[10];
    const float* W_ih1  = (const float*)d_in[11];
    const float* W_hh1  = (const float*)d_in[12];
    const float* b_ih1  = (const float*)d_in[13];
    const float* b_hh1  = (const float*)d_in[14];
    const float* W_out  = (const float*)d_in[15];
    const float* b_out  = (const float*)d_in[16];

    float* out = (float*)d_out;
    float* gat_seq = (float*)d_ws;                       //  8.4 MB
    float* h1  = gat_seq + (size_t)BS_TOT*64;            //  8.4 MB
    float* h2  = h1 + (size_t)BS_TOT*64;                 //  8.4 MB
    float* gxb = h2 + (size_t)BS_TOT*64;                 // 33.5 MB (shared by both layers)

    hipLaunchKernelGGL(gat_proj_kernel, dim3(BS_TOT/NB), dim3(256), 0, stream,
                       x, adj, W_gat, a_src, a_dst, W_proj, b_proj,
                       gat_seq, out + RECON_SIZE);
    hipLaunchKernelGGL(xproj_kernel, dim3(BS_TOT/64), dim3(256), 0, stream,
                       gat_seq, W_ih0, b_ih0, b_hh0, gxb);
    hipLaunchKernelGGL(lstm_rec_kernel, dim3(BBB), dim3(256), 0, stream,
                       gxb, W_hh0, h1);
    hipLaunchKernelGGL(xproj_kernel, dim3(BS_TOT/64), dim3(256), 0, stream,
                       h1, W_ih1, b_ih1, b_hh1, gxb);
    hipLaunchKernelGGL(lstm_rec_kernel, dim3(BBB), dim3(256), 0, stream,
                       gxb, W_hh1, h2);
    hipLaunchKernelGGL(recon_kernel, dim3(BS_TOT/8), dim3(256), 0, stream,
                       h2, W_out, b_out, out);
}

// Round 9
// 773.316 us; speedup vs baseline: 1.4273x; 1.1763x over previous
//
#include <hip/hip_runtime.h>
#include <math.h>

#define BS_TOT 32768
#define NN 30
#define HHD 8
#define GHH 16
#define LHH 64
#define SSS 512
#define BBB 64
#define RECON_SIZE (BBB*SSS*NN)   // 983040

__device__ __forceinline__ float fsigmoid(float x) {
    return 1.f / (1.f + __expf(-x));
}
__device__ __forceinline__ float ftanh(float x) {
    float ax = fabsf(x);
    float e = __expf(-2.f * ax);
    float r = (1.f - e) / (1.f + e);
    return copysignf(r, x);
}

// ---------------- K1: GAT + projection (fused) ----------------
#define NB 16
__global__ __launch_bounds__(256) void gat_proj_kernel(
    const float* __restrict__ x, const float* __restrict__ adj,
    const float* __restrict__ W_gat, const float* __restrict__ a_src,
    const float* __restrict__ a_dst, const float* __restrict__ W_proj,
    const float* __restrict__ b_proj, float* __restrict__ gat_seq,
    float* __restrict__ attn_out)
{
    __shared__ __align__(16) float gat[NB][480];
    __shared__ __align__(16) float wchunk[96*64];
    __shared__ float x_s[NB][32];
    __shared__ unsigned adjbits[32];

    const int t = threadIdx.x;
    const int bs_base = blockIdx.x * NB;

    for (int rep = 0; rep < 2; ++rep) {
        int idx = rep*256 + t;
        int bl = idx >> 5, j = idx & 31;
        if (j < NN) x_s[bl][j] = x[(bs_base + bl)*NN + j];
    }
    if (t < NN) {
        unsigned bits = 0;
        for (int j = 0; j < NN; ++j)
            if (adj[t*NN + j] != 0.0f) bits |= (1u << j);
        adjbits[t] = bits;
    }
    __syncthreads();

    const int wave = t >> 6, lane = t & 63;
    const int h = lane >> 5, i = lane & 31;
    const bool act = (i < NN);

    float wg[HHD];
    float s_h = 0.f, t_h = 0.f;
    #pragma unroll
    for (int d = 0; d < HHD; ++d) {
        float w = W_gat[h*HHD + d];
        wg[d] = w;
        s_h += w * a_src[h*HHD + d];
        t_h += w * a_dst[h*HHD + d];
    }

    for (int r = 0; r < 4; ++r) {
        const int bl = wave*4 + r;
        const int bs = bs_base + bl;
        const unsigned bits = act ? adjbits[i & 31] : 0u;
        const float xi = act ? x_s[bl][i] : 0.f;
        const float esrc = xi * s_h;

        float m = -1e30f;
        for (int j = 0; j < NN; ++j) {
            if (bits & (1u << j)) {
                float e = esrc + x_s[bl][j] * t_h;
                e = (e >= 0.f) ? e : 0.2f * e;
                m = fmaxf(m, e);
            }
        }
        float Z = 0.f, Sx = 0.f;
        for (int j = 0; j < NN; ++j) {
            if (bits & (1u << j)) {
                float e = esrc + x_s[bl][j] * t_h;
                e = (e >= 0.f) ? e : 0.2f * e;
                float p = expf(e - m);
                Z += p;
                Sx += p * x_s[bl][j];
            }
        }
        const float wsum = Sx / Z;

        if (act) {
            float tmp[8];
            #pragma unroll
            for (int d = 0; d < 8; ++d) {
                float v = wsum * wg[d];
                tmp[d] = (v > 0.f) ? v : expm1f(v);
            }
            float4 v0 = make_float4(tmp[0], tmp[1], tmp[2], tmp[3]);
            float4 v1 = make_float4(tmp[4], tmp[5], tmp[6], tmp[7]);
            *(float4*)&gat[bl][i*GHH + h*HHD]     = v0;
            *(float4*)&gat[bl][i*GHH + h*HHD + 4] = v1;
        }

        if ((bs & (SSS-1)) == (SSS-1)) {
            const int b = bs >> 9;
            for (int j = 0; j < NN; ++j) {
                float a = 0.f;
                if (bits & (1u << j)) {
                    float e = esrc + x_s[bl][j] * t_h;
                    e = (e >= 0.f) ? e : 0.2f * e;
                    a = expf(e - m) / Z;
                }
                float ao = __shfl_xor(a, 32, 64);
                if (act && h == 0)
                    attn_out[b*(NN*NN) + i*NN + j] = 0.5f * (a + ao);
            }
        }
    }
    __syncthreads();

    const int p = t & 63, grp = t >> 6;
    float acc0 = 0.f, acc1 = 0.f, acc2 = 0.f, acc3 = 0.f;
    for (int c = 0; c < 5; ++c) {
        #pragma unroll
        for (int rep = 0; rep < 24; ++rep)
            wchunk[rep*256 + t] = W_proj[c*6144 + rep*256 + t];
        __syncthreads();
        for (int kk = 0; kk < 96; kk += 4) {
            float4 g0 = *(const float4*)&gat[grp*4 + 0][c*96 + kk];
            float4 g1 = *(const float4*)&gat[grp*4 + 1][c*96 + kk];
            float4 g2 = *(const float4*)&gat[grp*4 + 2][c*96 + kk];
            float4 g3 = *(const float4*)&gat[grp*4 + 3][c*96 + kk];
            float w0 = wchunk[(kk+0)*64 + p];
            float w1 = wchunk[(kk+1)*64 + p];
            float w2 = wchunk[(kk+2)*64 + p];
            float w3 = wchunk[(kk+3)*64 + p];
            acc0 += g0.x*w0 + g0.y*w1 + g0.z*w2 + g0.w*w3;
            acc1 += g1.x*w0 + g1.y*w1 + g1.z*w2 + g1.w*w3;
            acc2 += g2.x*w0 + g2.y*w1 + g2.z*w2 + g2.w*w3;
            acc3 += g3.x*w0 + g3.y*w1 + g3.z*w2 + g3.w*w3;
        }
        __syncthreads();
    }
    const float bp = b_proj[p];
    gat_seq[(bs_base + grp*4 + 0)*64 + p] = fmaxf(acc0 + bp, 0.f);
    gat_seq[(bs_base + grp*4 + 1)*64 + p] = fmaxf(acc1 + bp, 0.f);
    gat_seq[(bs_base + grp*4 + 2)*64 + p] = fmaxf(acc2 + bp, 0.f);
    gat_seq[(bs_base + grp*4 + 3)*64 + p] = fmaxf(acc3 + bp, 0.f);
}

// ------- K2a: input projection (no recurrence -> fully parallel GEMM) -------
__global__ __launch_bounds__(256) void xproj_kernel(
    const float* __restrict__ xin,   // (BS, 64)
    const float* __restrict__ W,     // (256, 64) row-major
    const float* __restrict__ b_ih, const float* __restrict__ b_hh,
    float* __restrict__ gx)          // (BS, 256)
{
    __shared__ __align__(16) float xt[64][64];   // 16 KB
    const int t = threadIdx.x;
    const int r0 = blockIdx.x * 64;

    for (int i = t; i < 64*16; i += 256) {       // float4 units
        int r = i >> 4, c4 = (i & 15) << 2;
        *(float4*)&xt[r][c4] = *(const float4*)&xin[(size_t)(r0 + r)*64 + c4];
    }
    float4 w[16];
    #pragma unroll
    for (int i = 0; i < 16; ++i) w[i] = *(const float4*)&W[t*64 + 4*i];
    const float bias = b_ih[t] + b_hh[t];
    __syncthreads();

    for (int r = 0; r < 64; ++r) {
        float a0 = 0.f, a1 = 0.f, a2 = 0.f, a3 = 0.f;
        #pragma unroll
        for (int i = 0; i < 16; ++i) {
            float4 v = *(const float4*)&xt[r][4*i];   // wave-uniform -> broadcast
            a0 = fmaf(v.x, w[i].x, a0); a1 = fmaf(v.y, w[i].y, a1);
            a2 = fmaf(v.z, w[i].z, a2); a3 = fmaf(v.w, w[i].w, a3);
        }
        gx[(size_t)(r0 + r)*256 + t] = bias + ((a0 + a1) + (a2 + a3));
    }
}

// ------- K2b: LSTM recurrence, K-sliced register weights ----------
// 1024 threads: row = t>>2 (gate row), slice = t&3 (16-wide K slice).
// Each thread holds only 16 weight floats (4 float4 = ~16 VGPR) -> total
// demand ~45 VGPR, UNDER the allocator's observed ~88 cap, so residency is
// structural (R8 lesson: LDS-resident W costs 64KB of ds_read per step =
// 1520 cyc; R2-R7 lesson: >88 VGPR demand always spills).
// Reduce over slices: lanes are slice-interleaved -> 2 in-wave __shfl_xor.
__global__ __launch_bounds__(1024, 1) void lstm_rec_kernel(
    const float* __restrict__ gx,    // (B, S, 256) precomputed x-part + biases
    const float* __restrict__ W_hh,  // (256, 64)
    float* __restrict__ h_out)       // (B, S, 64)
{
    __shared__ float h_s[64];
    __shared__ float gates[256];

    const int t = threadIdx.x;
    const int b = blockIdx.x;
    const int row = t >> 2, slice = t & 3;
    const int sect = row >> 6;            // 0:i 1:f 2:g 3:o (wave-uniform)

    // 16 weight floats per thread
    const float4 w0 = *(const float4*)&W_hh[row*64 + slice*16 + 0];
    const float4 w1 = *(const float4*)&W_hh[row*64 + slice*16 + 4];
    const float4 w2 = *(const float4*)&W_hh[row*64 + slice*16 + 8];
    const float4 w3 = *(const float4*)&W_hh[row*64 + slice*16 + 12];

    if (t < 64) h_s[t] = 0.f;
    __syncthreads();

    const float* __restrict__ gxb = gx + (size_t)b * SSS * 256;
    float* __restrict__ hrow = h_out + (size_t)b * SSS * 64;

    float c = 0.f;
    float gx_cur = gxb[row];

    for (int tt = 0; tt < SSS; ++tt) {
        float gx_next = (tt + 1 < SSS) ? gxb[(size_t)(tt+1)*256 + row] : 0.f;

        const float4 h0 = *(const float4*)&h_s[slice*16 + 0];
        const float4 h1 = *(const float4*)&h_s[slice*16 + 4];
        const float4 h2 = *(const float4*)&h_s[slice*16 + 8];
        const float4 h3 = *(const float4*)&h_s[slice*16 + 12];

        float a0 = h0.x*w0.x + h0.y*w0.y + h0.z*w0.z + h0.w*w0.w;
        float a1 = h1.x*w1.x + h1.y*w1.y + h1.z*w1.z + h1.w*w1.w;
        float a2 = h2.x*w2.x + h2.y*w2.y + h2.z*w2.z + h2.w*w2.w;
        float a3 = h3.x*w3.x + h3.y*w3.y + h3.z*w3.z + h3.w*w3.w;
        float acc = (a0 + a1) + (a2 + a3);

        // reduce across the 4 slices (lanes row*4+0..3 are adjacent, in-wave)
        acc += __shfl_xor(acc, 1, 64);
        acc += __shfl_xor(acc, 2, 64);
        acc += gx_cur;

        const float a = (sect == 2) ? ftanh(acc) : fsigmoid(acc);
        if (slice == 0) gates[row] = a;
        __syncthreads();

        if (t < 64) {
            float ig = gates[t], fg = gates[64+t], gg = gates[128+t], og = gates[192+t];
            c = fg*c + ig*gg;
            float hv = og * ftanh(c);
            h_s[t] = hv;
            hrow[(size_t)tt*64 + t] = hv;
        }
        gx_cur = gx_next;
        __syncthreads();
    }
}

// ---------------- K3: recon = h2 @ W_out + b_out ----------------
__global__ __launch_bounds__(256) void recon_kernel(
    const float* __restrict__ h2, const float* __restrict__ W_out,
    const float* __restrict__ b_out, float* __restrict__ out)
{
    __shared__ __align__(16) float hl[8*64];
    const int t = threadIdx.x;
    const int bs_base = blockIdx.x * 8;

    hl[t]       = h2[(size_t)bs_base*64 + t];
    hl[256 + t] = h2[(size_t)bs_base*64 + 256 + t];
    __syncthreads();

    if (t < 240) {
        const int bl = t / 30;
        const int n  = t - bl*30;
        float acc = b_out[n];
        #pragma unroll
        for (int k = 0; k < 64; ++k)
            acc += hl[bl*64 + k] * W_out[k*NN + n];
        out[(size_t)(bs_base + bl)*NN + n] = acc;
    }
}

extern "C" void kernel_launch(void* const* d_in, const int* in_sizes, int n_in,
                              void* d_out, int out_size, void* d_ws, size_t ws_size,
                              hipStream_t stream)
{
    const float* x      = (const float*)d_in[0];
    const float* adj    = (const float*)d_in[1];
    const float* W_gat  = (const float*)d_in[2];
    const float* a_src  = (const float*)d_in[3];
    const float* a_dst  = (const float*)d_in[4];
    const float* W_proj = (const float*)d_in[5];
    const float* b_proj = (const float*)d_in[6];
    const float* W_ih0  = (const float*)d_in[7];
    const float* W_hh0  = (const float*)d_in[8];
    const float* b_ih0  = (const float*)d_in[9];
    const float* b_hh0  = (const float*)d_in[10];
    const float* W_ih1  = (const float*)d_in[11];
    const float* W_hh1  = (const float*)d_in[12];
    const float* b_ih1  = (const float*)d_in[13];
    const float* b_hh1  = (const float*)d_in[14];
    const float* W_out  = (const float*)d_in[15];
    const float* b_out  = (const float*)d_in[16];

    float* out = (float*)d_out;
    float* gat_seq = (float*)d_ws;                       //  8.4 MB
    float* h1  = gat_seq + (size_t)BS_TOT*64;            //  8.4 MB
    float* h2  = h1 + (size_t)BS_TOT*64;                 //  8.4 MB
    float* gxb = h2 + (size_t)BS_TOT*64;                 // 33.5 MB

    hipLaunchKernelGGL(gat_proj_kernel, dim3(BS_TOT/NB), dim3(256), 0, stream,
                       x, adj, W_gat, a_src, a_dst, W_proj, b_proj,
                       gat_seq, out + RECON_SIZE);
    hipLaunchKernelGGL(xproj_kernel, dim3(BS_TOT/64), dim3(256), 0, stream,
                       gat_seq, W_ih0, b_ih0, b_hh0, gxb);
    hipLaunchKernelGGL(lstm_rec_kernel, dim3(BBB), dim3(1024), 0, stream,
                       gxb, W_hh0, h1);
    hipLaunchKernelGGL(xproj_kernel, dim3(BS_TOT/64), dim3(256), 0, stream,
                       h1, W_ih1, b_ih1, b_hh1, gxb);
    hipLaunchKernelGGL(lstm_rec_kernel, dim3(BBB), dim3(1024), 0, stream,
                       gxb, W_hh1, h2);
    hipLaunchKernelGGL(recon_kernel, dim3(BS_TOT/8), dim3(256), 0, stream,
                       h2, W_out, b_out, out);
}